// Round 11
// baseline (4993.579 us; speedup 1.0000x reference)
//
#include <hip/hip_runtime.h>

#define TT 2048
#define WD 768
#define HH 512
#define G4 2048      // 4*H
#define NC 5
#define SENT 0xFFFFFFFFu   // owned sentinel (-NaN); |h|<1 can never produce it.
                           // h buffers memset to 0xFF at every launch.

typedef float f4 __attribute__((ext_vector_type(4)));
typedef unsigned int u4 __attribute__((ext_vector_type(4)));

// ---------------------------------------------------------------------------
// FUSED kernel: 576 wgs — R7 VERBATIM (4047-4063 us proven across R7/R10).
//   wgs   0..63 : LSTM recurrence, R0 protocol verbatim + zin tile-flag
//                 check + feats tail (proven sentinel polls, bit-exact dot).
//   wgs 64..575 : zin GEMM overlay (R6-proven), t-tiles fwd-asc / bwd-desc.
// ---------------------------------------------------------------------------
__global__ __launch_bounds__(256, 1) void fused_main(
    const int* __restrict__ sent, const float* __restrict__ emb,
    const float* __restrict__ Wih_f, const float* __restrict__ bih_f, const float* __restrict__ bhh_f,
    const float* __restrict__ Wih_b, const float* __restrict__ bih_b, const float* __restrict__ bhh_b,
    const float* __restrict__ Whh_f, const float* __restrict__ Whh_b,
    float* __restrict__ zin_f, float* __restrict__ zin_b,
    unsigned int* __restrict__ hw_f, unsigned int* __restrict__ hw_b,
    unsigned int* __restrict__ zcnt,
    const float* __restrict__ fc_w, const float* __restrict__ fc_b,
    float* __restrict__ feats6)
{
    __shared__ float As[16][128];
    __shared__ float Bs[16][128];
    __shared__ float hs[HH];
    __shared__ float zb[256];

    const int tid = threadIdx.x;

    if (blockIdx.x >= 64) {
        // ================= GEMM role (R6 verbatim) =================
        const int lin  = blockIdx.x - 64;      // [0,512)
        const int pair = lin >> 5;             // [0,16): production order
        const int sub  = lin & 31;
        const int dirn = sub & 1;
        const int gx   = sub >> 1;             // [0,16)
        const int ty   = dirn ? (15 - pair) : pair;   // bwd consumes high t first

        const float* Wih = dirn ? Wih_b : Wih_f;
        const float* bih = dirn ? bih_b : bih_f;
        const float* bhh = dirn ? bhh_b : bhh_f;
        float* zin = dirn ? zin_b : zin_f;

        const int t0 = ty * 128;
        const int g0 = gx * 128;
        const int tm = tid >> 4, tn = tid & 15;

        float acc[8][8];
#pragma unroll
        for (int a = 0; a < 8; a++)
#pragma unroll
            for (int b = 0; b < 8; b++) acc[a][b] = 0.f;

        for (int kt = 0; kt < 48; ++kt) {
            const int k0 = kt * 16;
#pragma unroll
            for (int u = 0; u < 2; ++u) {
                const int s = tid * 2 + u;
                const int m = s >> 2, kq = s & 3;
                const int rowA = sent[t0 + m];
                float4 av = *(const float4*)(emb + (size_t)rowA * WD + k0 + kq * 4);
                As[kq * 4 + 0][m] = av.x; As[kq * 4 + 1][m] = av.y;
                As[kq * 4 + 2][m] = av.z; As[kq * 4 + 3][m] = av.w;
                float4 bv = *(const float4*)(Wih + (size_t)(g0 + m) * WD + k0 + kq * 4);
                Bs[kq * 4 + 0][m] = bv.x; Bs[kq * 4 + 1][m] = bv.y;
                Bs[kq * 4 + 2][m] = bv.z; Bs[kq * 4 + 3][m] = bv.w;
            }
            __syncthreads();
#pragma unroll
            for (int kk = 0; kk < 16; ++kk) {
                float4 a0 = *(const float4*)&As[kk][tm * 8];
                float4 a1 = *(const float4*)&As[kk][tm * 8 + 4];
                float4 b0 = *(const float4*)&Bs[kk][tn * 8];
                float4 b1 = *(const float4*)&Bs[kk][tn * 8 + 4];
                float av8[8] = {a0.x, a0.y, a0.z, a0.w, a1.x, a1.y, a1.z, a1.w};
                float bv8[8] = {b0.x, b0.y, b0.z, b0.w, b1.x, b1.y, b1.z, b1.w};
#pragma unroll
                for (int a = 0; a < 8; a++)
#pragma unroll
                    for (int b = 0; b < 8; b++) acc[a][b] += av8[a] * bv8[b];
            }
            __syncthreads();
        }
        float bias[8];
#pragma unroll
        for (int b = 0; b < 8; b++) { int g = g0 + tn * 8 + b; bias[b] = bih[g] + bhh[g]; }
#pragma unroll
        for (int a = 0; a < 8; a++) {
            const int t = t0 + tm * 8 + a;
            float* op = zin + (size_t)t * G4 + g0 + tn * 8;
            f4 o0 = {acc[a][0] + bias[0], acc[a][1] + bias[1], acc[a][2] + bias[2], acc[a][3] + bias[3]};
            f4 o1 = {acc[a][4] + bias[4], acc[a][5] + bias[5], acc[a][6] + bias[6], acc[a][7] + bias[7]};
            // sc1: write-through to LLC (within-kernel cross-XCD visibility)
            asm volatile("global_store_dwordx4 %0, %1, off sc1" :: "v"(op), "v"(o0) : "memory");
            asm volatile("global_store_dwordx4 %0, %1, off sc1" :: "v"(op + 4), "v"(o1) : "memory");
        }
        __syncthreads();    // per-wave vmcnt(0) drain precedes the barrier
        if (tid == 0) atomicAdd(&zcnt[dirn * 16 + ty], 1u);   // device-scope
        return;
    }

    // ================= LSTM role (R0 verbatim + tile-flag check) =================
    const int bid = blockIdx.x;
    const int d = bid >> 5;          // 0 fwd, 1 bwd
    const int k = bid & 31;
    const float* zin = d ? zin_b : zin_f;
    const float* Whh = d ? Whh_b : Whh_f;
    unsigned int* hw = d ? hw_b : hw_f;

    const int q = tid >> 6;          // wave = column segment (128 cols)
    const int r = tid & 63;          // gate row within wg
    const int gate = r >> 4, jj = r & 15;
    const int grow = gate * HH + k * 16 + jj;      // global gate row [0,2048)

    const f4* wp = (const f4*)(Whh + (size_t)grow * HH + q * 128);
    f4 w[32];
#pragma unroll
    for (int i = 0; i < 32; ++i) w[i] = wp[i];     // plain loads: correct waitcnt
#pragma unroll
    for (int i = 0; i < 32; ++i)
        asm volatile("" : "+a"(w[i]));             // home the values in AGPRs

    float c = 0.f;
    const int l = tid;               // wave0 lane id (used when tid<64)
    const int g = l >> 4, j = l & 15;     // gate / unit for gate phase
    const int n16 = k * 16 + j;           // hidden index for gate phase

    int readyty = -1;                // last verified zin tile (wave0 only)

    for (int it = 0; it < TT; ++it) {
        const int t = d ? (TT - 1 - it) : it;

        // wave0: zin value for (gate g, unit j) — issued before the poll
        float z = 0.f;
        if (tid < 64) {
            const int tyc = t >> 7;
            if (tyc != readyty) {            // once per 128 steps, wave-uniform
                const unsigned int* cp = zcnt + d * 16 + tyc;
                unsigned int cv;
                do {
                    asm volatile("global_load_dword %0, %1, off sc0 sc1\n\t"
                                 "s_waitcnt vmcnt(0)"
                                 : "=v"(cv) : "v"(cp) : "memory");
                } while (cv < 16u);
                readyty = tyc;
            }
            z = zin[(size_t)t * G4 + g * HH + n16];
        }

        if (it > 0 && tid < 64) {
            const int tp = d ? (t + 1) : (t - 1);
            const unsigned int* pa = hw + (size_t)tp * HH + l * 8;
            u4 a0, a1;
            for (;;) {
                asm volatile(
                    "global_load_dwordx4 %0, %2, off sc0 sc1\n\t"
                    "global_load_dwordx4 %1, %2, off offset:16 sc0 sc1\n\t"
                    "s_waitcnt vmcnt(0)"
                    : "=v"(a0), "=v"(a1) : "v"(pa) : "memory");
                if (a0.x != SENT && a0.y != SENT && a0.z != SENT && a0.w != SENT &&
                    a1.x != SENT && a1.y != SENT && a1.z != SENT && a1.w != SENT) break;
            }
            u4* hd = (u4*)(hs + l * 8);
            hd[0] = a0; hd[1] = a1;
        }
        __syncthreads();                                   // B1: hs ready

        // keep weights homed in AGPRs across the loop (re-pin each iter)
#pragma unroll
        for (int i = 0; i < 32; ++i) asm volatile("" : "+a"(w[i]));

        float part = 0.f;
        if (it > 0) {
            const f4* hv = ((const f4*)hs) + (q << 5);     // wave-uniform broadcast
#pragma unroll
            for (int i = 0; i < 32; ++i) {
                f4 h4 = hv[i];
                part += w[i].x * h4.x + w[i].y * h4.y + w[i].z * h4.z + w[i].w * h4.w;
            }
        }
        zb[tid] = part;                                    // zb[q*64 + r]
        __syncthreads();                                   // B2: partials ready

        if (tid < 64) {
            // same summation order as R0 (bit-exact): qq = 0..3
            float s = zb[l] + zb[64 + l] + zb[128 + l] + zb[192 + l];
            const float pre = z + s;
            float act;
            if (g == 2) act = tanhf(pre);                  // g gate
            else        act = 1.f / (1.f + expf(-pre));    // i, f, o gates
            const float gi = __shfl(act, j);
            const float gf = __shfl(act, j + 16);
            const float gg = __shfl(act, j + 32);
            const float go = __shfl(act, j + 48);
            if (l < 16) {
                c = gf * c + gi * gg;
                const float hval = go * tanhf(c);
                __hip_atomic_store(&hw[(size_t)t * HH + k * 16 + l],
                                   __float_as_uint(hval),
                                   __ATOMIC_RELAXED, __HIP_MEMORY_SCOPE_AGENT);
            }
        }
        // 2 barriers suffice (see R0 comments).
    }

    // ================= feats tail (R7 verbatim, stride-6 stores) =============
    {
        const int wgid = d * 32 + k;
        float* const rowbuf = (q < 2) ? (&As[0][0] + q * 1024)
                                      : (&Bs[0][0] + (q - 2) * 1024);
        for (int n = 0; n < 8; ++n) {
            const int t = (wgid * 4 + q) * 8 + n;
            {
                const unsigned int* pa = hw_f + (size_t)t * HH + r * 8;
                u4 a0, a1;
                for (;;) {
                    asm volatile(
                        "global_load_dwordx4 %0, %2, off sc0 sc1\n\t"
                        "global_load_dwordx4 %1, %2, off offset:16 sc0 sc1\n\t"
                        "s_waitcnt vmcnt(0)"
                        : "=v"(a0), "=v"(a1) : "v"(pa) : "memory");
                    if (a0.x != SENT && a0.y != SENT && a0.z != SENT && a0.w != SENT &&
                        a1.x != SENT && a1.y != SENT && a1.z != SENT && a1.w != SENT) break;
                }
                u4* dstp = (u4*)(rowbuf + r * 8);
                dstp[0] = a0; dstp[1] = a1;
            }
            {
                const unsigned int* pa = hw_b + (size_t)t * HH + r * 8;
                u4 a0, a1;
                for (;;) {
                    asm volatile(
                        "global_load_dwordx4 %0, %2, off sc0 sc1\n\t"
                        "global_load_dwordx4 %1, %2, off offset:16 sc0 sc1\n\t"
                        "s_waitcnt vmcnt(0)"
                        : "=v"(a0), "=v"(a1) : "v"(pa) : "memory");
                    if (a0.x != SENT && a0.y != SENT && a0.z != SENT && a0.w != SENT &&
                        a1.x != SENT && a1.y != SENT && a1.z != SENT && a1.w != SENT) break;
                }
                u4* dstp = (u4*)(rowbuf + HH + r * 8);
                dstp[0] = a0; dstp[1] = a1;
            }
            float facc[NC] = {0.f, 0.f, 0.f, 0.f, 0.f};
            for (int m = 0; m < 16; ++m) {
                const int cg = r + m * 64;
                const float hv = rowbuf[cg];   // [h_f | h_b] layout, bit-exact
#pragma unroll
                for (int i = 0; i < NC; i++) facc[i] += hv * fc_w[i * (2 * HH) + cg];
            }
#pragma unroll
            for (int i = 0; i < NC; i++) {
#pragma unroll
                for (int off = 32; off; off >>= 1) facc[i] += __shfl_xor(facc[i], off);
            }
            if (r == 0) {
#pragma unroll
                for (int i = 0; i < NC; i++)
                    feats6[(size_t)t * 6 + i] = facc[i] + fc_b[i];   // stride 6
            }
        }
    }
}

// ---------------------------------------------------------------------------
// Viterbi. R10 post-mortem: the ~620 us cost (720 cy/step, invariant across
// R6/R7/R10 variants) is the cmp/cndmask ARGMAX chain — the layer-carry
// dependence threads through 20 v_cmp + 40 v_cndmask per step with mask-reg
// write->read hazards. Fix: carry the VALUE through a pure max tree
// (v_max/v_max3, no mask regs, exact & associative -> bit-identical value);
// recover the parent index OFF the critical path as "first j with v_j ==
// max" (identical to serial first-wins-on-strictly-greater semantics) via 5
// independent compares + an integer min tree. Layer chain: add->max3->max3->
// add ~= 25 cy/step. Backtrack: R7's integer-exact chunk maps, now with
// compile-time-unrolled indexing (rule #20: runtime-indexed arrays spill).
// Every value and index provably equals the serial reference.
// ---------------------------------------------------------------------------
__global__ void viterbi_kernel(const float* __restrict__ feats6,
                               const float* __restrict__ trans,
                               float* __restrict__ out)
{
    __shared__ float fs6[TT * 6];              // 49152 B
    __shared__ unsigned short par[TT];         //  4096 B
    __shared__ unsigned int maps[64];
    __shared__ int bidx[64];
    const int tid = threadIdx.x;

    for (int i = tid; i < TT * 6 / 4; i += 64)
        ((f4*)fs6)[i] = ((const f4*)feats6)[i];
    float tr[25];
#pragma unroll
    for (int i = 0; i < 25; i++) tr[i] = trans[i];
    __syncthreads();

    float layer[NC];
#pragma unroll
    for (int i = 0; i < NC; i++) layer[i] = fs6[i] + tr[i * 5 + 3];

    // one Viterbi step: value via max tree (exact), parent = first j == max
#define VSTEP(FT0, FT1, FT2, FT3, FT4, SIDX)                                   \
    do {                                                                       \
        float nl[NC]; int pk = 0;                                              \
        _Pragma("unroll")                                                      \
        for (int i = 0; i < NC; i++) {                                         \
            const float v0 = tr[i * 5 + 0] + layer[0];                         \
            const float v1 = tr[i * 5 + 1] + layer[1];                         \
            const float v2 = tr[i * 5 + 2] + layer[2];                         \
            const float v3 = tr[i * 5 + 3] + layer[3];                         \
            const float v4 = tr[i * 5 + 4] + layer[4];                         \
            const float m = fmaxf(fmaxf(fmaxf(fmaxf(v0, v1), v2), v3), v4);    \
            const int c0 = (v0 == m) ? 0 : 7;                                  \
            const int c1 = (v1 == m) ? 1 : 7;                                  \
            const int c2 = (v2 == m) ? 2 : 7;                                  \
            const int c3 = (v3 == m) ? 3 : 7;                                  \
            const int c4 = (v4 == m) ? 4 : 7;                                  \
            const int bj = min(min(min(min(c0, c1), c2), c3), c4);             \
            const float ftv[NC] = {FT0, FT1, FT2, FT3, FT4};                   \
            nl[i] = ftv[i] + m;                                                \
            pk |= bj << (3 * i);                                               \
        }                                                                      \
        _Pragma("unroll")                                                      \
        for (int i = 0; i < NC; i++) layer[i] = nl[i];                         \
        if (tid == 0) par[SIDX] = (unsigned short)pk;                          \
    } while (0)

    // ---- forward scan: 255 blocks of 8 steps + 7-step tail (2047 steps) ----
    for (int b = 0; b < 255; ++b) {
        const int s0 = b * 8;
        float2 fb[8][3];
#pragma unroll
        for (int u = 0; u < 8; ++u) {
            const float2* fp = (const float2*)(fs6 + (size_t)(s0 + u + 1) * 6);
            fb[u][0] = fp[0]; fb[u][1] = fp[1]; fb[u][2] = fp[2];
        }
#pragma unroll
        for (int u = 0; u < 8; ++u)
            VSTEP(fb[u][0].x, fb[u][0].y, fb[u][1].x, fb[u][1].y, fb[u][2].x, s0 + u);
    }
    for (int s = 2040; s < TT - 1; ++s) {      // tail
        const float* fp = fs6 + (size_t)(s + 1) * 6;
        VSTEP(fp[0], fp[1], fp[2], fp[3], fp[4], s);
    }
#undef VSTEP

    // final: best = max over j of layer[j]+tr[20+j]; idx0 = first attaining
    float fv[NC];
#pragma unroll
    for (int jj = 0; jj < NC; jj++) fv[jj] = layer[jj] + tr[20 + jj];
    const float best = fmaxf(fmaxf(fmaxf(fmaxf(fv[0], fv[1]), fv[2]), fv[3]), fv[4]);
    int idx0;
    {
        const int c0 = (fv[0] == best) ? 0 : 7;
        const int c1 = (fv[1] == best) ? 1 : 7;
        const int c2 = (fv[2] == best) ? 2 : 7;
        const int c3 = (fv[3] == best) ? 3 : 7;
        const int c4 = (fv[4] == best) ? 4 : 7;
        idx0 = min(min(min(min(c0, c1), c2), c3), c4);
    }
    __syncthreads();

    // ---- parallel backtrack (integer-exact, compile-time-indexed) ----
    const int slo = tid * 32;
    int preg[32];
#pragma unroll
    for (int u = 0; u < 32; ++u) {
        int su = slo + u; if (su > TT - 2) su = TT - 2;   // clamp (unused dups)
        preg[u] = (int)par[su];
    }
    int m0 = 0, m1 = 1, m2 = 2, m3 = 3, m4 = 4;
#pragma unroll
    for (int u = 31; u >= 0; --u) {
        if (slo + u <= TT - 2) {
            const int pv = preg[u];
            m0 = (pv >> (3 * m0)) & 7;
            m1 = (pv >> (3 * m1)) & 7;
            m2 = (pv >> (3 * m2)) & 7;
            m3 = (pv >> (3 * m3)) & 7;
            m4 = (pv >> (3 * m4)) & 7;
        }
    }
    maps[tid] = (unsigned)(m0 | (m1 << 3) | (m2 << 6) | (m3 << 9) | (m4 << 12));
    __syncthreads();
    if (tid == 0) {
        int e = idx0;                     // idx entering chunk 63 (= idx_{TT-1})
        for (int cc = 63; cc >= 0; --cc) {
            bidx[cc] = e;
            e = (int)((maps[cc] >> (3 * e)) & 7u);
        }
    }
    __syncthreads();
    {
        int e = bidx[tid];
#pragma unroll
        for (int u = 31; u >= 0; --u) {
            if (slo + u <= TT - 2) {
                e = (preg[u] >> (3 * e)) & 7;
                out[slo + u] = (float)e;
            }
        }
    }
    if (tid == 0) { out[TT - 1] = (float)idx0; out[TT] = best; }
}

// ---------------------------------------------------------------------------
extern "C" void kernel_launch(void* const* d_in, const int* in_sizes, int n_in,
                              void* d_out, int out_size, void* d_ws, size_t ws_size,
                              hipStream_t stream) {
    const int*   sent   = (const int*)d_in[0];
    const float* emb    = (const float*)d_in[1];
    const float* Wih_f  = (const float*)d_in[2];
    const float* Whh_f  = (const float*)d_in[3];
    const float* bih_f  = (const float*)d_in[4];
    const float* bhh_f  = (const float*)d_in[5];
    const float* Wih_b  = (const float*)d_in[6];
    const float* Whh_b  = (const float*)d_in[7];
    const float* bih_b  = (const float*)d_in[8];
    const float* bhh_b  = (const float*)d_in[9];
    const float* fc_w   = (const float*)d_in[10];
    const float* fc_b   = (const float*)d_in[11];
    const float* trans  = (const float*)d_in[12];
    float* out = (float*)d_out;

    char* ws = (char*)d_ws;
    float* zin_f = (float*)ws;                                   // 16 MB @ 0
    float* zin_b = (float*)(ws + (size_t)16777216);              // 16 MB @ 16M
    unsigned int* hw_f = (unsigned int*)(ws + (size_t)33554432); //  4 MB @ 32M
    unsigned int* hw_b = (unsigned int*)(ws + (size_t)37748736); //  4 MB @ 36M
    float* feats6 = (float*)(ws + (size_t)41943040);             // 48 KB @ 40M (stride 6)
    unsigned int* zcnt = (unsigned int*)(ws + (size_t)42008576); // 128 B @ 40M+64K

    // OWN the sentinel: h buffers = 0xFFFFFFFF (-NaN, impossible h)
    hipMemsetAsync(hw_f, 0xFF, (size_t)8388608, stream);         // covers hw_f + hw_b
    hipMemsetAsync(zcnt, 0, (size_t)128, stream);                // zin tile flags

    fused_main<<<576, 256, 0, stream>>>(sent, emb,
                                        Wih_f, bih_f, bhh_f,
                                        Wih_b, bih_b, bhh_b,
                                        Whh_f, Whh_b,
                                        zin_f, zin_b, hw_f, hw_b, zcnt,
                                        fc_w, fc_b, feats6);

    viterbi_kernel<<<1, 64, 0, stream>>>(feats6, trans, out);
}